// Round 1
// baseline (338.614 us; speedup 1.0000x reference)
//
#include <hip/hip_runtime.h>
#include <math.h>

// Problem constants
constexpr int BN = 64, CH = 3, HH = 512, WW = 512;
constexpr int HO = 256, WO = 256;          // (512-2)/2+1
constexpr int HW = HH * WW;                // 262144
constexpr int HOWO = HO * WO;              // 65536
constexpr float EPS_F = 1e-8f;

// ---- deterministic float atomic min/max via sign-split integer trick ----
__device__ __forceinline__ void atomicMinF(float* a, float v) {
    if (v >= 0.0f) atomicMin((int*)a, __float_as_int(v));
    else           atomicMax((unsigned int*)a, __float_as_uint(v));
}
__device__ __forceinline__ void atomicMaxF(float* a, float v) {
    if (v >= 0.0f) atomicMax((int*)a, __float_as_int(v));
    else           atomicMin((unsigned int*)a, __float_as_uint(v));
}

__global__ void k_init(float* mm) {
    mm[0] = __int_as_float(0x7F800000);   // +inf
    mm[1] = __int_as_float(0xFF800000);   // -inf
}

// Pass 1: global min/max of gray = mean(x, axis=C). float4 per thread-iter.
__global__ __launch_bounds__(256) void k_minmax(const float* __restrict__ x,
                                                float* __restrict__ mm) {
    const int total4 = BN * HW / 4;        // 4,194,304 float4 groups
    const float c13 = 1.0f / 3.0f;
    float vmin = __int_as_float(0x7F800000);
    float vmax = __int_as_float(0xFF800000);
    for (int i = blockIdx.x * blockDim.x + threadIdx.x; i < total4;
         i += gridDim.x * blockDim.x) {
        int pix = i * 4;
        int b   = pix / HW;
        int rem = pix - b * HW;
        const float* base = x + b * (CH * HW) + rem;
        float4 a0 = *(const float4*)(base);
        float4 a1 = *(const float4*)(base + HW);
        float4 a2 = *(const float4*)(base + 2 * HW);
        float g0 = (a0.x + a1.x + a2.x) * c13;
        float g1 = (a0.y + a1.y + a2.y) * c13;
        float g2 = (a0.z + a1.z + a2.z) * c13;
        float g3 = (a0.w + a1.w + a2.w) * c13;
        vmin = fminf(vmin, fminf(fminf(g0, g1), fminf(g2, g3)));
        vmax = fmaxf(vmax, fmaxf(fmaxf(g0, g1), fmaxf(g2, g3)));
    }
    // wave-64 reduce
    #pragma unroll
    for (int off = 32; off > 0; off >>= 1) {
        vmin = fminf(vmin, __shfl_down(vmin, off, 64));
        vmax = fmaxf(vmax, __shfl_down(vmax, off, 64));
    }
    __shared__ float smin[4], smax[4];
    int lane = threadIdx.x & 63, wid = threadIdx.x >> 6;
    if (lane == 0) { smin[wid] = vmin; smax[wid] = vmax; }
    __syncthreads();
    if (threadIdx.x == 0) {
        float m = smin[0], M = smax[0];
        #pragma unroll
        for (int i = 1; i < 4; ++i) { m = fminf(m, smin[i]); M = fmaxf(M, smax[i]); }
        atomicMinF(&mm[0], m);
        atomicMaxF(&mm[1], M);
    }
}

// fast tanh: tanh(x) = 1 - 2/(e^{2x}+1), via hw exp2 + rcp (abs err ~1e-6)
__device__ __forceinline__ float fast_tanh(float x) {
    float t = __builtin_amdgcn_exp2f(x * 2.8853900817779268f);  // e^{2x}
    return 1.0f - 2.0f * __builtin_amdgcn_rcpf(t + 1.0f);
}

// Pass 2: each thread handles 2 horizontally-adjacent patches (float4 rows).
__global__ __launch_bounds__(256) void k_main(const float* __restrict__ x,
                                              const float* __restrict__ wts,  // (2,4,3)
                                              const float* __restrict__ pw,   // (4,4,1,1)
                                              const float* __restrict__ pb,   // (4,)
                                              const float* __restrict__ mm,
                                              float* __restrict__ out) {
    const int WP = WO / 2;                 // 128 patch-pairs per row
    int idx = blockIdx.x * blockDim.x + threadIdx.x;   // exact grid: BN*HO*WP
    int wp = idx % WP;
    int t  = idx / WP;
    int ho = t % HO;
    int b  = t / HO;

    float pmin = mm[0];
    float inv  = 1.0f / (mm[1] - pmin + EPS_F);
    // fold sin(pi*u) = hw_sin(0.5*u)  [v_sin_f32 takes revolutions]
    float sscale = inv * 0.5f;

    // per-layer per-qubit constants (wave-uniform; tiny)
    const float inv2pi = 0.15915494309189535f;
    float c0[2][4], s1[2][4], b2[2][4];
    #pragma unroll
    for (int l = 0; l < 2; ++l)
        #pragma unroll
        for (int q = 0; q < 4; ++q) {
            c0[l][q] = __builtin_amdgcn_cosf(wts[(l * 4 + q) * 3 + 0] * inv2pi);
            s1[l][q] = __builtin_amdgcn_sinf(wts[(l * 4 + q) * 3 + 1] * inv2pi);
            b2[l][q] = wts[(l * 4 + q) * 3 + 2];
        }

    const float c13 = 1.0f / 3.0f;
    const float* xb = x + b * (CH * HW) + (2 * ho) * WW + 4 * wp;
    float4 r0c0 = *(const float4*)(xb);
    float4 r1c0 = *(const float4*)(xb + WW);
    float4 r0c1 = *(const float4*)(xb + HW);
    float4 r1c1 = *(const float4*)(xb + HW + WW);
    float4 r0c2 = *(const float4*)(xb + 2 * HW);
    float4 r1c2 = *(const float4*)(xb + 2 * HW + WW);

    float g0x = (r0c0.x + r0c1.x + r0c2.x) * c13;
    float g0y = (r0c0.y + r0c1.y + r0c2.y) * c13;
    float g0z = (r0c0.z + r0c1.z + r0c2.z) * c13;
    float g0w = (r0c0.w + r0c1.w + r0c2.w) * c13;
    float g1x = (r1c0.x + r1c1.x + r1c2.x) * c13;
    float g1y = (r1c0.y + r1c1.y + r1c2.y) * c13;
    float g1z = (r1c0.z + r1c1.z + r1c2.z) * c13;
    float g1w = (r1c0.w + r1c1.w + r1c2.w) * c13;

    // patch layout: q = {(r0,c0), (r0,c1), (r1,c0), (r1,c1)}
    float e[2][4];
    e[0][0] = g0x; e[0][1] = g0y; e[0][2] = g1x; e[0][3] = g1y;
    e[1][0] = g0z; e[1][1] = g0w; e[1][2] = g1z; e[1][3] = g1w;

    #pragma unroll
    for (int p = 0; p < 2; ++p) {
        #pragma unroll
        for (int q = 0; q < 4; ++q)
            e[p][q] = __builtin_amdgcn_sinf((e[p][q] - pmin) * sscale);
        #pragma unroll
        for (int l = 0; l < 2; ++l) {
            float m[4];
            #pragma unroll
            for (int q = 0; q < 4; ++q)
                m[q] = e[p][q] * c0[l][q] + e[p][(q + 1) & 3] * s1[l][q] + b2[l][q];
            #pragma unroll
            for (int q = 0; q < 4; ++q)
                e[p][q] = fast_tanh(m[q]);
        }
    }

    int obase = b * (4 * HOWO) + ho * WO + 2 * wp;
    #pragma unroll
    for (int o = 0; o < 4; ++o) {
        float w0 = pw[o * 4 + 0], w1 = pw[o * 4 + 1], w2 = pw[o * 4 + 2], w3 = pw[o * 4 + 3];
        float2 v;
        v.x = pb[o] + e[0][0] * w0 + e[0][1] * w1 + e[0][2] * w2 + e[0][3] * w3;
        v.y = pb[o] + e[1][0] * w0 + e[1][1] * w1 + e[1][2] * w2 + e[1][3] * w3;
        *(float2*)(out + obase + o * HOWO) = v;
    }
}

extern "C" void kernel_launch(void* const* d_in, const int* in_sizes, int n_in,
                              void* d_out, int out_size, void* d_ws, size_t ws_size,
                              hipStream_t stream) {
    const float* x   = (const float*)d_in[0];
    const float* wts = (const float*)d_in[1];
    const float* pw  = (const float*)d_in[2];
    const float* pb  = (const float*)d_in[3];
    float* out = (float*)d_out;
    float* mm  = (float*)d_ws;

    k_init<<<1, 1, 0, stream>>>(mm);
    k_minmax<<<2048, 256, 0, stream>>>(x, mm);
    const int threads = BN * HO * (WO / 2);          // 2,097,152
    k_main<<<threads / 256, 256, 0, stream>>>(x, wts, pw, pb, mm, out);
}

// Round 3
// 314.142 us; speedup vs baseline: 1.0779x; 1.0779x over previous
//
#include <hip/hip_runtime.h>
#include <hip/hip_fp16.h>

// Problem constants
constexpr int BN = 64, CH = 3, HH = 512, WW = 512;
constexpr int HO = 256, WO = 256;
constexpr int HW = HH * WW;              // 262144
constexpr int HOWO = HO * WO;            // 65536
constexpr float EPS_F = 1e-8f;

constexpr int TPB = 256;
constexpr int GROUPS = BN * HO * (WO / 4);   // 1,048,576 groups of 4 patches
constexpr int ABLOCKS = 2048;
constexpr int AT = ABLOCKS * TPB;            // 524,288 threads
constexpr int AITERS = GROUPS / AT;          // 2
constexpr int CBLOCKS = GROUPS / TPB;        // 4096

// ws layout: [gray fp16: GROUPS*16 halfs = 32 MiB][partials: 2*ABLOCKS floats][mm: 2 floats]
constexpr size_t GRAY_HALFS = (size_t)GROUPS * 16;

// tanh(x) = 1 - 2/(e^{2x}+1) via hw exp2 + rcp (abs err ~1e-6, saturates correctly)
__device__ __forceinline__ float fast_tanh(float x) {
    float t = __builtin_amdgcn_exp2f(x * 2.8853900817779268f);  // e^{2x}
    return 1.0f - 2.0f * __builtin_amdgcn_rcpf(t + 1.0f);
}

// Pass 1: gray = mean(x, C); write fp16 gray to ws; per-block min/max partials.
__global__ __launch_bounds__(TPB) void k_pass1(const float* __restrict__ x,
                                               float4* __restrict__ gray4,
                                               float* __restrict__ part) {
    const int tid = blockIdx.x * TPB + threadIdx.x;
    const float c13 = 1.0f / 3.0f;
    float vmin = __int_as_float(0x7F800000);
    float vmax = __int_as_float(0xFF800000);

    #pragma unroll
    for (int it = 0; it < AITERS; ++it) {
        int grp = it * AT + tid;         // group of 4 consecutive patches
        int b   = grp >> 14;             // 16384 groups per image
        int rem = grp & 16383;
        int ho  = rem >> 6;              // 64 groups per patch-row
        int wp  = rem & 63;
        const float* base = x + b * (CH * HW) + (2 * ho) * WW + 8 * wp;

        float row0[8], row1[8];
        #pragma unroll
        for (int c = 0; c < CH; ++c) {
            const float* pc = base + c * HW;
            float4 u0 = *(const float4*)(pc);
            float4 u1 = *(const float4*)(pc + 4);
            float4 v0 = *(const float4*)(pc + WW);
            float4 v1 = *(const float4*)(pc + WW + 4);
            float uu[8] = {u0.x, u0.y, u0.z, u0.w, u1.x, u1.y, u1.z, u1.w};
            float vv[8] = {v0.x, v0.y, v0.z, v0.w, v1.x, v1.y, v1.z, v1.w};
            if (c == 0) {
                #pragma unroll
                for (int k = 0; k < 8; ++k) { row0[k] = uu[k]; row1[k] = vv[k]; }
            } else {
                #pragma unroll
                for (int k = 0; k < 8; ++k) { row0[k] += uu[k]; row1[k] += vv[k]; }
            }
        }
        #pragma unroll
        for (int k = 0; k < 8; ++k) {
            row0[k] *= c13; row1[k] *= c13;
            vmin = fminf(vmin, fminf(row0[k], row1[k]));
            vmax = fmaxf(vmax, fmaxf(row0[k], row1[k]));
        }
        // pack 16 grays: per patch p: h2[2p]=(r0c0,r0c1), h2[2p+1]=(r1c0,r1c1)
        alignas(16) __half2 h2[8];
        #pragma unroll
        for (int p = 0; p < 4; ++p) {
            h2[2 * p]     = __floats2half2_rn(row0[2 * p], row0[2 * p + 1]);
            h2[2 * p + 1] = __floats2half2_rn(row1[2 * p], row1[2 * p + 1]);
        }
        gray4[(size_t)grp * 2]     = *(const float4*)&h2[0];
        gray4[(size_t)grp * 2 + 1] = *(const float4*)&h2[4];
    }

    // wave + block min/max reduce (deterministic)
    #pragma unroll
    for (int off = 32; off > 0; off >>= 1) {
        vmin = fminf(vmin, __shfl_down(vmin, off, 64));
        vmax = fmaxf(vmax, __shfl_down(vmax, off, 64));
    }
    __shared__ float sm[8];
    int lane = threadIdx.x & 63, wid = threadIdx.x >> 6;
    if (lane == 0) { sm[wid] = vmin; sm[4 + wid] = vmax; }
    __syncthreads();
    if (threadIdx.x == 0) {
        part[2 * blockIdx.x]     = fminf(fminf(sm[0], sm[1]), fminf(sm[2], sm[3]));
        part[2 * blockIdx.x + 1] = fmaxf(fmaxf(sm[4], sm[5]), fmaxf(sm[6], sm[7]));
    }
}

// Reduce 2048 partial pairs -> mm[0]=min, mm[1]=max
__global__ __launch_bounds__(TPB) void k_reduce(const float* __restrict__ part,
                                                float* __restrict__ mm) {
    float m = __int_as_float(0x7F800000);
    float M = __int_as_float(0xFF800000);
    #pragma unroll
    for (int i = 0; i < ABLOCKS / TPB; ++i) {
        int j = i * TPB + threadIdx.x;
        m = fminf(m, part[2 * j]);
        M = fmaxf(M, part[2 * j + 1]);
    }
    #pragma unroll
    for (int off = 32; off > 0; off >>= 1) {
        m = fminf(m, __shfl_down(m, off, 64));
        M = fmaxf(M, __shfl_down(M, off, 64));
    }
    __shared__ float sm[8];
    int lane = threadIdx.x & 63, wid = threadIdx.x >> 6;
    if (lane == 0) { sm[wid] = m; sm[4 + wid] = M; }
    __syncthreads();
    if (threadIdx.x == 0) {
        mm[0] = fminf(fminf(sm[0], sm[1]), fminf(sm[2], sm[3]));
        mm[1] = fmaxf(fmaxf(sm[4], sm[5]), fmaxf(sm[6], sm[7]));
    }
}

// Pass 2: read fp16 gray (cache-hot), quantum chain + projection, write out.
__global__ __launch_bounds__(TPB) void k_main(const float4* __restrict__ gray4,
                                              const float* __restrict__ wts,
                                              const float* __restrict__ pw,
                                              const float* __restrict__ pb,
                                              const float* __restrict__ mm,
                                              float* __restrict__ out) {
    int grp = blockIdx.x * TPB + threadIdx.x;    // exact grid: GROUPS
    int b   = grp >> 14;
    int rem = grp & 16383;
    int ho  = rem >> 6;
    int wp  = rem & 63;

    float pmin   = mm[0];
    // sin(pi*u) = hw_sin(u/2)   [v_sin_f32 takes revolutions]
    float sscale = 0.5f / (mm[1] - pmin + EPS_F);

    // wave-uniform constants
    const float inv2pi = 0.15915494309189535f;
    float c0[2][4], s1[2][4], b2[2][4];
    #pragma unroll
    for (int l = 0; l < 2; ++l)
        #pragma unroll
        for (int q = 0; q < 4; ++q) {
            c0[l][q] = __builtin_amdgcn_cosf(wts[(l * 4 + q) * 3 + 0] * inv2pi);
            s1[l][q] = __builtin_amdgcn_sinf(wts[(l * 4 + q) * 3 + 1] * inv2pi);
            b2[l][q] = wts[(l * 4 + q) * 3 + 2];
        }
    float pwr[4][4], pbr[4];
    #pragma unroll
    for (int o = 0; o < 4; ++o) {
        pbr[o] = pb[o];
        #pragma unroll
        for (int q = 0; q < 4; ++q) pwr[o][q] = pw[o * 4 + q];
    }

    alignas(16) __half2 h2[8];
    *(float4*)&h2[0] = gray4[(size_t)grp * 2];
    *(float4*)&h2[4] = gray4[(size_t)grp * 2 + 1];

    float e[4][4];
    #pragma unroll
    for (int p = 0; p < 4; ++p) {
        e[p][0] = __low2float(h2[2 * p]);     e[p][1] = __high2float(h2[2 * p]);
        e[p][2] = __low2float(h2[2 * p + 1]); e[p][3] = __high2float(h2[2 * p + 1]);
    }
    #pragma unroll
    for (int p = 0; p < 4; ++p)
        #pragma unroll
        for (int q = 0; q < 4; ++q)
            e[p][q] = __builtin_amdgcn_sinf((e[p][q] - pmin) * sscale);
    #pragma unroll
    for (int l = 0; l < 2; ++l)
        #pragma unroll
        for (int p = 0; p < 4; ++p) {
            float mq[4];
            #pragma unroll
            for (int q = 0; q < 4; ++q)
                mq[q] = e[p][q] * c0[l][q] + e[p][(q + 1) & 3] * s1[l][q] + b2[l][q];
            #pragma unroll
            for (int q = 0; q < 4; ++q) e[p][q] = fast_tanh(mq[q]);
        }

    float* ob = out + b * (4 * HOWO) + ho * WO + 4 * wp;
    #pragma unroll
    for (int o = 0; o < 4; ++o) {
        float4 v;
        float* vp = &v.x;
        #pragma unroll
        for (int p = 0; p < 4; ++p) {
            float acc = pbr[o];
            #pragma unroll
            for (int q = 0; q < 4; ++q) acc += e[p][q] * pwr[o][q];
            vp[p] = acc;
        }
        *(float4*)(ob + o * HOWO) = v;
    }
}

extern "C" void kernel_launch(void* const* d_in, const int* in_sizes, int n_in,
                              void* d_out, int out_size, void* d_ws, size_t ws_size,
                              hipStream_t stream) {
    const float* x   = (const float*)d_in[0];
    const float* wts = (const float*)d_in[1];
    const float* pw  = (const float*)d_in[2];
    const float* pb  = (const float*)d_in[3];
    float* out = (float*)d_out;

    float4* gray4 = (float4*)d_ws;
    float*  part  = (float*)((char*)d_ws + GRAY_HALFS * sizeof(__half));
    float*  mm    = part + 2 * ABLOCKS;

    k_pass1 <<<ABLOCKS, TPB, 0, stream>>>(x, gray4, part);
    k_reduce<<<1,       TPB, 0, stream>>>(part, mm);
    k_main  <<<CBLOCKS, TPB, 0, stream>>>(gray4, wts, pw, pb, mm, out);
}